// Round 3
// baseline (218.996 us; speedup 1.0000x reference)
//
#include <hip/hip_runtime.h>
#include <math.h>

// Problem constants (fixed by the reference setup_inputs)
#define BB 2
#define VV 3
#define CC 8
#define HH 128
#define WW 160
#define DD 64
constexpr int HW = HH * WW;
constexpr int NPIX = BB * HW;            // 40960
constexpr int PX_PER_BLOCK = 32;         // consecutive pixels per block
constexpr int CHUNKS = 8;                // depth chunks (8 depths each)
constexpr int DEPTHS_PER_CHUNK = DD / CHUNKS;   // 8

// ---------------------------------------------------------------------------
// Prep: transpose features [V,B,C,H,W] -> [V,B,H,W,C] so one bilinear corner
// is 8 contiguous floats (2x float4) instead of 8 stride-HW scalar gathers.
// ---------------------------------------------------------------------------
__global__ __launch_bounds__(256)
void transpose_feats(const float* __restrict__ feats, float* __restrict__ ft)
{
    const int t = blockIdx.x * blockDim.x + threadIdx.x;   // one thread per (vb, hw)
    if (t >= VV * BB * HW) return;
    const int vb = t / HW;
    const int hw = t - vb * HW;
    const float* src = feats + (size_t)vb * CC * HW + hw;
    float* dst = ft + (size_t)vb * HW * CC + (size_t)hw * CC;
    float4 lo, hi;
    lo.x = src[0 * HW]; lo.y = src[1 * HW]; lo.z = src[2 * HW]; lo.w = src[3 * HW];
    hi.x = src[4 * HW]; hi.y = src[5 * HW]; hi.z = src[6 * HW]; hi.w = src[7 * HW];
    ((float4*)dst)[0] = lo;
    ((float4*)dst)[1] = hi;
}

// ---------------------------------------------------------------------------
// Fused: block = 32 consecutive pixels x 8 depth chunks (4 waves).
// Wave = 32 px x 2 chunks -> corner gathers span ~2 contiguous clusters.
// ---------------------------------------------------------------------------
__global__ __launch_bounds__(256, 4)
void depthnet_fused(const float* __restrict__ ft,      // [V,B,H,W,C] transposed
                    const float* __restrict__ proj,    // [B,V,3,4]
                    const float* __restrict__ depthv,  // [B,D,H,W]
                    const float* __restrict__ regw,    // [C]
                    float* __restrict__ out)           // [B,H,W]
{
    __shared__ float sm_m[PX_PER_BLOCK * 4];
    __shared__ float sm_l[PX_PER_BLOCK * 4];
    __shared__ float sm_s[PX_PER_BLOCK * 4];

    const int tid   = threadIdx.x;
    const int lane  = tid & 63;
    const int wave  = tid >> 6;              // 0..3
    const int px    = lane & 31;             // pixel within block
    const int sub   = lane >> 5;             // 0/1
    const int chunk = wave * 2 + sub;        // 0..7
    const int pixel = blockIdx.x * PX_PER_BLOCK + px;

    const int b  = (pixel >= HW) ? 1 : 0;
    const int hw = pixel - b * HW;
    const int h  = hw / WW;
    const int w  = hw - h * WW;

    // reference-view features (channel-contiguous)
    const float* f0 = ft + ((size_t)b * HW + hw) * CC;
    float rf[CC], rf2[CC];
    {
        float4 lo = ((const float4*)f0)[0];
        float4 hi = ((const float4*)f0)[1];
        rf[0] = lo.x; rf[1] = lo.y; rf[2] = lo.z; rf[3] = lo.w;
        rf[4] = hi.x; rf[5] = hi.y; rf[6] = hi.z; rf[7] = hi.w;
    }
#pragma unroll
    for (int c = 0; c < CC; ++c) rf2[c] = rf[c] * rf[c];

    // per-view projection rows applied to (x, y, 1); T columns
    float Rp[2][3], Tv[2][3];
    const float xf = (float)w, yf = (float)h;
#pragma unroll
    for (int v = 0; v < 2; ++v) {
        const float* M = proj + ((size_t)b * VV + (v + 1)) * 12;
#pragma unroll
        for (int i = 0; i < 3; ++i) {
            Rp[v][i] = M[i * 4 + 0] * xf + M[i * 4 + 1] * yf + M[i * 4 + 2];
            Tv[v][i] = M[i * 4 + 3];
        }
    }

    const float* fsrc0 = ft + ((size_t)(1 * BB + b)) * HW * CC;
    const float* fsrc1 = ft + ((size_t)(2 * BB + b)) * HW * CC;

    float m = -INFINITY, l = 0.f, s = 0.f;

    const float* dvp = depthv + (size_t)b * DD * HW + hw;
    const int d0 = chunk * DEPTHS_PER_CHUNK;

#pragma unroll 4
    for (int dd = 0; dd < DEPTHS_PER_CHUNK; ++dd) {
        const int d = d0 + dd;
        const float dv = dvp[(size_t)d * HW];
        const float inv_dv = __builtin_amdgcn_rcpf(dv);

        float sum[CC], sq[CC];
#pragma unroll
        for (int c = 0; c < CC; ++c) { sum[c] = rf[c]; sq[c] = rf2[c]; }
        float nmask = 1.0f;

#pragma unroll
        for (int v = 0; v < 2; ++v) {
            const float* fb = (v == 0) ? fsrc0 : fsrc1;
            const float sx = Rp[v][0] + Tv[v][0] * inv_dv;
            const float sy = Rp[v][1] + Tv[v][1] * inv_dv;
            const float sz = Rp[v][2] + Tv[v][2] * inv_dv;
            const float rsz = __builtin_amdgcn_rcpf(sz);
            const float ix = sx * rsz;       // == (gx+1)*0.5*(W-1)
            const float iy = sy * rsz;
            // in-mask: gx in (-1,1) <=> ix in (0, W-1)
            nmask += ((ix > 0.f) && (ix < (float)(WW - 1)) &&
                      (iy > 0.f) && (iy < (float)(HH - 1))) ? 1.0f : 0.0f;
            const float x0f = floorf(ix), y0f = floorf(iy);
            const float wx1 = ix - x0f, wy1 = iy - y0f;
            const float wx0 = 1.f - wx1, wy0 = 1.f - wy1;
            const float x1f = x0f + 1.f, y1f = y0f + 1.f;
            const bool vx0 = (x0f >= 0.f) && (x0f <= (float)(WW - 1));
            const bool vx1 = (x1f >= 0.f) && (x1f <= (float)(WW - 1));
            const bool vy0 = (y0f >= 0.f) && (y0f <= (float)(HH - 1));
            const bool vy1 = (y1f >= 0.f) && (y1f <= (float)(HH - 1));
            const float w00 = wx0 * wy0 * ((vx0 && vy0) ? 1.f : 0.f);
            const float w01 = wx1 * wy0 * ((vx1 && vy0) ? 1.f : 0.f);
            const float w10 = wx0 * wy1 * ((vx0 && vy1) ? 1.f : 0.f);
            const float w11 = wx1 * wy1 * ((vx1 && vy1) ? 1.f : 0.f);
            const int x0c = (int)fminf(fmaxf(x0f, 0.f), (float)(WW - 1));
            const int x1c = (int)fminf(fmaxf(x1f, 0.f), (float)(WW - 1));
            const int y0c = (int)fminf(fmaxf(y0f, 0.f), (float)(HH - 1));
            const int y1c = (int)fminf(fmaxf(y1f, 0.f), (float)(HH - 1));
            const int i00 = (y0c * WW + x0c) * CC;
            const int i01 = (y0c * WW + x1c) * CC;
            const int i10 = (y1c * WW + x0c) * CC;
            const int i11 = (y1c * WW + x1c) * CC;

            float val[CC];
            {   // corner 00
                float4 lo = *(const float4*)(fb + i00);
                float4 hi = *(const float4*)(fb + i00 + 4);
                val[0] = lo.x * w00; val[1] = lo.y * w00; val[2] = lo.z * w00; val[3] = lo.w * w00;
                val[4] = hi.x * w00; val[5] = hi.y * w00; val[6] = hi.z * w00; val[7] = hi.w * w00;
            }
            {   // corner 01
                float4 lo = *(const float4*)(fb + i01);
                float4 hi = *(const float4*)(fb + i01 + 4);
                val[0] += lo.x * w01; val[1] += lo.y * w01; val[2] += lo.z * w01; val[3] += lo.w * w01;
                val[4] += hi.x * w01; val[5] += hi.y * w01; val[6] += hi.z * w01; val[7] += hi.w * w01;
            }
            {   // corner 10
                float4 lo = *(const float4*)(fb + i10);
                float4 hi = *(const float4*)(fb + i10 + 4);
                val[0] += lo.x * w10; val[1] += lo.y * w10; val[2] += lo.z * w10; val[3] += lo.w * w10;
                val[4] += hi.x * w10; val[5] += hi.y * w10; val[6] += hi.z * w10; val[7] += hi.w * w10;
            }
            {   // corner 11
                float4 lo = *(const float4*)(fb + i11);
                float4 hi = *(const float4*)(fb + i11 + 4);
                val[0] += lo.x * w11; val[1] += lo.y * w11; val[2] += lo.z * w11; val[3] += lo.w * w11;
                val[4] += hi.x * w11; val[5] += hi.y * w11; val[6] += hi.z * w11; val[7] += hi.w * w11;
            }

#pragma unroll
            for (int c = 0; c < CC; ++c) {
                sum[c] += val[c];
                sq[c]  += val[c] * val[c];
            }
        }

        const float cnt = __builtin_amdgcn_rcpf(nmask);
        float t1 = 0.f, t2 = 0.f;
#pragma unroll
        for (int c = 0; c < CC; ++c) {
            t1 += regw[c] * sq[c];                    // regw wave-uniform -> scalar
            t2 += (regw[c] * sum[c]) * sum[c];
        }
        const float cost = cnt * t1 - (cnt * cnt) * t2;

        // branch-free online softmax update, weighted by dv
        const float M = fmaxf(m, cost);
        const float e_old = __expf(m - M);     // exp(-inf)=0 on first iter
        const float e_new = __expf(cost - M);
        l = l * e_old + e_new;
        s = s * e_old + e_new * dv;
        m = M;
    }

    // merge the two chunks within the wave (lanes xor 32)
    {
        const float m2 = __shfl_xor(m, 32, 64);
        const float l2 = __shfl_xor(l, 32, 64);
        const float s2 = __shfl_xor(s, 32, 64);
        const float M  = fmaxf(m, m2);
        const float e1 = __expf(m - M);
        const float e2 = __expf(m2 - M);
        l = l * e1 + l2 * e2;
        s = s * e1 + s2 * e2;
        m = M;
    }

    if (lane < 32) {
        sm_m[wave * PX_PER_BLOCK + px] = m;
        sm_l[wave * PX_PER_BLOCK + px] = l;
        sm_s[wave * PX_PER_BLOCK + px] = s;
    }
    __syncthreads();

    if (tid < PX_PER_BLOCK) {
        float M = sm_m[tid], L = sm_l[tid], S = sm_s[tid];
#pragma unroll
        for (int wv = 1; wv < 4; ++wv) {
            const float m2 = sm_m[wv * PX_PER_BLOCK + tid];
            const float l2 = sm_l[wv * PX_PER_BLOCK + tid];
            const float s2 = sm_s[wv * PX_PER_BLOCK + tid];
            const float Mn = fmaxf(M, m2);
            const float e1 = __expf(M - Mn);
            const float e2 = __expf(m2 - Mn);
            L = L * e1 + l2 * e2;
            S = S * e1 + s2 * e2;
            M = Mn;
        }
        out[blockIdx.x * PX_PER_BLOCK + tid] = S / L;
    }
}

extern "C" void kernel_launch(void* const* d_in, const int* in_sizes, int n_in,
                              void* d_out, int out_size, void* d_ws, size_t ws_size,
                              hipStream_t stream) {
    const float* feats  = (const float*)d_in[0];
    const float* proj   = (const float*)d_in[1];
    const float* depthv = (const float*)d_in[2];
    const float* regw   = (const float*)d_in[3];
    float* out = (float*)d_out;
    float* ft  = (float*)d_ws;   // [V,B,H,W,C] = 3.93 MB

    {
        const int n = VV * BB * HW;                       // 122880
        const int block = 256;
        const int grid = (n + block - 1) / block;
        hipLaunchKernelGGL(transpose_feats, dim3(grid), dim3(block), 0, stream,
                           feats, ft);
    }
    {
        const int grid = NPIX / PX_PER_BLOCK;             // 1280 = 5 blocks/CU
        hipLaunchKernelGGL(depthnet_fused, dim3(grid), dim3(256), 0, stream,
                           ft, proj, depthv, regw, out);
    }
}

// Round 4
// 105.191 us; speedup vs baseline: 2.0819x; 2.0819x over previous
//
#include <hip/hip_runtime.h>
#include <math.h>

// Problem constants (fixed by the reference setup_inputs)
#define BB 2
#define VV 3
#define CC 8
#define HH 128
#define WW 160
#define DD 64
constexpr int HW = HH * WW;
constexpr int NPIX = BB * HW;            // 40960
constexpr int PX_PER_BLOCK = 16;         // consecutive pixels per block
constexpr int CHUNKS = 16;               // depth chunks per pixel
constexpr int DEPTHS_PER_CHUNK = DD / CHUNKS;   // 4

// ---------------------------------------------------------------------------
// Prep: transpose features [V,B,C,H,W] -> [V,B,H,W,C] so one bilinear corner
// is 8 contiguous floats (2x float4) instead of 8 stride-HW scalar gathers.
// ---------------------------------------------------------------------------
__global__ __launch_bounds__(256)
void transpose_feats(const float* __restrict__ feats, float* __restrict__ ft)
{
    const int t = blockIdx.x * blockDim.x + threadIdx.x;   // one thread per (vb, hw)
    if (t >= VV * BB * HW) return;
    const int vb = t / HW;
    const int hw = t - vb * HW;
    const float* src = feats + (size_t)vb * CC * HW + hw;
    float* dst = ft + (size_t)vb * HW * CC + (size_t)hw * CC;
    float4 lo, hi;
    lo.x = src[0 * HW]; lo.y = src[1 * HW]; lo.z = src[2 * HW]; lo.w = src[3 * HW];
    hi.x = src[4 * HW]; hi.y = src[5 * HW]; hi.z = src[6 * HW]; hi.w = src[7 * HW];
    ((float4*)dst)[0] = lo;
    ((float4*)dst)[1] = hi;
}

// ---------------------------------------------------------------------------
// Fused: block = 16 consecutive pixels x 16 depth chunks (4 waves).
// Wave = 16 contiguous px x 4 chunks -> corner gathers span ~4 contiguous
// pixel clusters. NO unroll pragma, NO launch-bounds waves arg: round-3's
// combination spilled ~600 B/thread to scratch (199 MB WRITE_SIZE).
// ---------------------------------------------------------------------------
__global__ __launch_bounds__(256)
void depthnet_fused(const float* __restrict__ ft,      // [V,B,H,W,C] transposed
                    const float* __restrict__ proj,    // [B,V,3,4]
                    const float* __restrict__ depthv,  // [B,D,H,W]
                    const float* __restrict__ regw,    // [C]
                    float* __restrict__ out)           // [B,H,W]
{
    __shared__ float sm_m[4 * PX_PER_BLOCK];
    __shared__ float sm_l[4 * PX_PER_BLOCK];
    __shared__ float sm_s[4 * PX_PER_BLOCK];

    const int tid   = threadIdx.x;
    const int lane  = tid & 63;
    const int wave  = tid >> 6;              // 0..3
    const int px    = lane & 15;             // pixel within block
    const int sub   = lane >> 4;             // 0..3
    const int chunk = wave * 4 + sub;        // 0..15
    const int pixel = blockIdx.x * PX_PER_BLOCK + px;

    const int b  = (pixel >= HW) ? 1 : 0;
    const int hw = pixel - b * HW;
    const int h  = hw / WW;
    const int w  = hw - h * WW;

    // reference-view features (channel-contiguous)
    const float* f0 = ft + ((size_t)b * HW + hw) * CC;
    float rf[CC], rf2[CC];
    {
        float4 lo = ((const float4*)f0)[0];
        float4 hi = ((const float4*)f0)[1];
        rf[0] = lo.x; rf[1] = lo.y; rf[2] = lo.z; rf[3] = lo.w;
        rf[4] = hi.x; rf[5] = hi.y; rf[6] = hi.z; rf[7] = hi.w;
    }
#pragma unroll
    for (int c = 0; c < CC; ++c) rf2[c] = rf[c] * rf[c];

    // per-view projection rows applied to (x, y, 1); T columns
    float Rp[2][3], Tv[2][3];
    const float xf = (float)w, yf = (float)h;
#pragma unroll
    for (int v = 0; v < 2; ++v) {
        const float* M = proj + ((size_t)b * VV + (v + 1)) * 12;
#pragma unroll
        for (int i = 0; i < 3; ++i) {
            Rp[v][i] = M[i * 4 + 0] * xf + M[i * 4 + 1] * yf + M[i * 4 + 2];
            Tv[v][i] = M[i * 4 + 3];
        }
    }

    const float* fsrc0 = ft + ((size_t)(1 * BB + b)) * HW * CC;
    const float* fsrc1 = ft + ((size_t)(2 * BB + b)) * HW * CC;

    float m = -INFINITY, l = 0.f, s = 0.f;

    const float* dvp = depthv + (size_t)b * DD * HW + hw;
    const int d0 = chunk * DEPTHS_PER_CHUNK;

    for (int dd = 0; dd < DEPTHS_PER_CHUNK; ++dd) {
        const int d = d0 + dd;
        const float dv = dvp[(size_t)d * HW];
        const float inv_dv = __builtin_amdgcn_rcpf(dv);

        float sum[CC], sq[CC];
#pragma unroll
        for (int c = 0; c < CC; ++c) { sum[c] = rf[c]; sq[c] = rf2[c]; }
        float nmask = 1.0f;

#pragma unroll
        for (int v = 0; v < 2; ++v) {
            const float* fb = (v == 0) ? fsrc0 : fsrc1;
            const float sx = Rp[v][0] + Tv[v][0] * inv_dv;
            const float sy = Rp[v][1] + Tv[v][1] * inv_dv;
            const float sz = Rp[v][2] + Tv[v][2] * inv_dv;
            const float rsz = __builtin_amdgcn_rcpf(sz);
            const float ix = sx * rsz;       // == (gx+1)*0.5*(W-1)
            const float iy = sy * rsz;
            // in-mask: gx in (-1,1) <=> ix in (0, W-1)
            nmask += ((ix > 0.f) && (ix < (float)(WW - 1)) &&
                      (iy > 0.f) && (iy < (float)(HH - 1))) ? 1.0f : 0.0f;
            const float x0f = floorf(ix), y0f = floorf(iy);
            const float wx1 = ix - x0f, wy1 = iy - y0f;
            const float wx0 = 1.f - wx1, wy0 = 1.f - wy1;
            const float x1f = x0f + 1.f, y1f = y0f + 1.f;
            const bool vx0 = (x0f >= 0.f) && (x0f <= (float)(WW - 1));
            const bool vx1 = (x1f >= 0.f) && (x1f <= (float)(WW - 1));
            const bool vy0 = (y0f >= 0.f) && (y0f <= (float)(HH - 1));
            const bool vy1 = (y1f >= 0.f) && (y1f <= (float)(HH - 1));
            const float w00 = wx0 * wy0 * ((vx0 && vy0) ? 1.f : 0.f);
            const float w01 = wx1 * wy0 * ((vx1 && vy0) ? 1.f : 0.f);
            const float w10 = wx0 * wy1 * ((vx0 && vy1) ? 1.f : 0.f);
            const float w11 = wx1 * wy1 * ((vx1 && vy1) ? 1.f : 0.f);
            const int x0c = (int)fminf(fmaxf(x0f, 0.f), (float)(WW - 1));
            const int x1c = (int)fminf(fmaxf(x1f, 0.f), (float)(WW - 1));
            const int y0c = (int)fminf(fmaxf(y0f, 0.f), (float)(HH - 1));
            const int y1c = (int)fminf(fmaxf(y1f, 0.f), (float)(HH - 1));
            const int i00 = (y0c * WW + x0c) * CC;
            const int i01 = (y0c * WW + x1c) * CC;
            const int i10 = (y1c * WW + x0c) * CC;
            const int i11 = (y1c * WW + x1c) * CC;

            float val[CC];
            {   // corner 00
                float4 lo = *(const float4*)(fb + i00);
                float4 hi = *(const float4*)(fb + i00 + 4);
                val[0] = lo.x * w00; val[1] = lo.y * w00; val[2] = lo.z * w00; val[3] = lo.w * w00;
                val[4] = hi.x * w00; val[5] = hi.y * w00; val[6] = hi.z * w00; val[7] = hi.w * w00;
            }
            {   // corner 01
                float4 lo = *(const float4*)(fb + i01);
                float4 hi = *(const float4*)(fb + i01 + 4);
                val[0] += lo.x * w01; val[1] += lo.y * w01; val[2] += lo.z * w01; val[3] += lo.w * w01;
                val[4] += hi.x * w01; val[5] += hi.y * w01; val[6] += hi.z * w01; val[7] += hi.w * w01;
            }
            {   // corner 10
                float4 lo = *(const float4*)(fb + i10);
                float4 hi = *(const float4*)(fb + i10 + 4);
                val[0] += lo.x * w10; val[1] += lo.y * w10; val[2] += lo.z * w10; val[3] += lo.w * w10;
                val[4] += hi.x * w10; val[5] += hi.y * w10; val[6] += hi.z * w10; val[7] += hi.w * w10;
            }
            {   // corner 11
                float4 lo = *(const float4*)(fb + i11);
                float4 hi = *(const float4*)(fb + i11 + 4);
                val[0] += lo.x * w11; val[1] += lo.y * w11; val[2] += lo.z * w11; val[3] += lo.w * w11;
                val[4] += hi.x * w11; val[5] += hi.y * w11; val[6] += hi.z * w11; val[7] += hi.w * w11;
            }

#pragma unroll
            for (int c = 0; c < CC; ++c) {
                sum[c] += val[c];
                sq[c]  += val[c] * val[c];
            }
        }

        const float cnt = __builtin_amdgcn_rcpf(nmask);
        float t1 = 0.f, t2 = 0.f;
#pragma unroll
        for (int c = 0; c < CC; ++c) {
            t1 += regw[c] * sq[c];                    // regw wave-uniform -> scalar
            t2 += (regw[c] * sum[c]) * sum[c];
        }
        const float cost = cnt * t1 - (cnt * cnt) * t2;

        // branch-free online softmax update, weighted by dv
        const float M = fmaxf(m, cost);
        const float e_old = __expf(m - M);     // exp(-inf)=0 on first iter
        const float e_new = __expf(cost - M);
        l = l * e_old + e_new;
        s = s * e_old + e_new * dv;
        m = M;
    }

    // merge the 4 chunks within the wave (lanes xor 16, 32)
#pragma unroll
    for (int off = 16; off < 64; off <<= 1) {
        const float m2 = __shfl_xor(m, off, 64);
        const float l2 = __shfl_xor(l, off, 64);
        const float s2 = __shfl_xor(s, off, 64);
        const float M  = fmaxf(m, m2);
        const float e1 = __expf(m - M);
        const float e2 = __expf(m2 - M);
        l = l * e1 + l2 * e2;
        s = s * e1 + s2 * e2;
        m = M;
    }

    if (lane < PX_PER_BLOCK) {
        sm_m[wave * PX_PER_BLOCK + px] = m;
        sm_l[wave * PX_PER_BLOCK + px] = l;
        sm_s[wave * PX_PER_BLOCK + px] = s;
    }
    __syncthreads();

    if (tid < PX_PER_BLOCK) {
        float M = sm_m[tid], L = sm_l[tid], S = sm_s[tid];
#pragma unroll
        for (int wv = 1; wv < 4; ++wv) {
            const float m2 = sm_m[wv * PX_PER_BLOCK + tid];
            const float l2 = sm_l[wv * PX_PER_BLOCK + tid];
            const float s2 = sm_s[wv * PX_PER_BLOCK + tid];
            const float Mn = fmaxf(M, m2);
            const float e1 = __expf(M - Mn);
            const float e2 = __expf(m2 - Mn);
            L = L * e1 + l2 * e2;
            S = S * e1 + s2 * e2;
            M = Mn;
        }
        out[blockIdx.x * PX_PER_BLOCK + tid] = S / L;
    }
}

extern "C" void kernel_launch(void* const* d_in, const int* in_sizes, int n_in,
                              void* d_out, int out_size, void* d_ws, size_t ws_size,
                              hipStream_t stream) {
    const float* feats  = (const float*)d_in[0];
    const float* proj   = (const float*)d_in[1];
    const float* depthv = (const float*)d_in[2];
    const float* regw   = (const float*)d_in[3];
    float* out = (float*)d_out;
    float* ft  = (float*)d_ws;   // [V,B,H,W,C] = 3.93 MB

    {
        const int n = VV * BB * HW;                       // 122880
        const int block = 256;
        const int grid = (n + block - 1) / block;
        hipLaunchKernelGGL(transpose_feats, dim3(grid), dim3(block), 0, stream,
                           feats, ft);
    }
    {
        const int grid = NPIX / PX_PER_BLOCK;             // 2560 blocks
        hipLaunchKernelGGL(depthnet_fused, dim3(grid), dim3(256), 0, stream,
                           ft, proj, depthv, regw, out);
    }
}